// Round 3
// baseline (1733.460 us; speedup 1.0000x reference)
//
#include <hip/hip_runtime.h>
#include <hip/hip_bf16.h>

// Resubmission of round-2 kernel; round-2 bench failed at container
// acquisition ("MI355X container failed twice"), not in the test.

#define Bc 4
#define Tc 256
#define Nc 4096
#define Kc 64
#define DEGc 4
#define Lc (Tc - 1)
#define NNZc (Bc * Nc * DEGc)
#define NPB 8                         // blocks (slices) per batch
#define TPB 512                       // threads per scan block
#define TPB_EM 256
#define NODES_PER (Nc / NPB)          // 512 -> one node per thread
#define LOG_N 8.31776616671934f

__device__ __forceinline__ float cohLoadF(const float* p) {
  return __hip_atomic_load((float*)p, __ATOMIC_RELAXED, __HIP_MEMORY_SCOPE_AGENT);
}
__device__ __forceinline__ void cohStoreF(float* p, float v) {
  __hip_atomic_store(p, v, __ATOMIC_RELAXED, __HIP_MEMORY_SCOPE_AGENT);
}

template <int NT>
__device__ __forceinline__ float blockSumT(float v, volatile float* red) {
#pragma unroll
  for (int o = 1; o < 64; o <<= 1) v += __shfl_xor(v, o, 64);
  __syncthreads();
  if ((threadIdx.x & 63) == 0) red[threadIdx.x >> 6] = v;
  __syncthreads();
  float s = 0.f;
#pragma unroll
  for (int k = 0; k < NT / 64; ++k) s += red[k];
  return s;
}
template <int NT>
__device__ __forceinline__ float blockMaxT(float v, volatile float* red) {
#pragma unroll
  for (int o = 1; o < 64; o <<= 1) v = fmaxf(v, __shfl_xor(v, o, 64));
  __syncthreads();
  if ((threadIdx.x & 63) == 0) red[threadIdx.x >> 6] = v;
  __syncthreads();
  float m = -INFINITY;
#pragma unroll
  for (int k = 0; k < NT / 64; ++k) m = fmaxf(m, red[k]);
  return m;
}

// em[r][n] = log_softmax(obs[r,:] @ W)[n], one block per row r = b*T + t
__global__ __launch_bounds__(TPB_EM) void em_kernel(const float* __restrict__ obs,
                                                    const float* __restrict__ W,
                                                    float* __restrict__ em) {
  const int r = blockIdx.x, tid = threadIdx.x;
  __shared__ float o[Kc];
  __shared__ float red[8];
  if (tid < Kc) o[tid] = obs[(size_t)r * Kc + tid];
  __syncthreads();
  float4 acc[4];
#pragma unroll
  for (int gI = 0; gI < 4; ++gI) acc[gI] = make_float4(0.f, 0.f, 0.f, 0.f);
  const float4* W4 = (const float4*)W;
  for (int k = 0; k < Kc; ++k) {
    const float ov = o[k];
    const float4* wr = W4 + (size_t)k * (Nc / 4);
#pragma unroll
    for (int gI = 0; gI < 4; ++gI) {
      float4 w = wr[gI * 256 + tid];
      acc[gI].x = fmaf(ov, w.x, acc[gI].x);
      acc[gI].y = fmaf(ov, w.y, acc[gI].y);
      acc[gI].z = fmaf(ov, w.z, acc[gI].z);
      acc[gI].w = fmaf(ov, w.w, acc[gI].w);
    }
  }
  float m = -INFINITY;
#pragma unroll
  for (int gI = 0; gI < 4; ++gI)
    m = fmaxf(m, fmaxf(fmaxf(acc[gI].x, acc[gI].y), fmaxf(acc[gI].z, acc[gI].w)));
  m = blockMaxT<TPB_EM>(m, red);
  float s = 0.f;
#pragma unroll
  for (int gI = 0; gI < 4; ++gI)
    s += __expf(acc[gI].x - m) + __expf(acc[gI].y - m) + __expf(acc[gI].z - m) + __expf(acc[gI].w - m);
  s = blockSumT<TPB_EM>(s, red);
  const float lse = m + __logf(s);
  float4* em4 = (float4*)em;
#pragma unroll
  for (int gI = 0; gI < 4; ++gI) {
    float4 w = acc[gI];
    w.x -= lse; w.y -= lse; w.z -= lse; w.w -= lse;
    em4[(size_t)r * (Nc / 4) + gI * 256 + tid] = w;
  }
}

// grid = B*NPB blocks of TPB threads; thread tid of (b, sl) owns node sl*512+tid
// and its 4 out-edges. No global atomics on data: LDS scatter -> dense per-slice
// partials via device-scope stores -> barrier -> dense gather of NPB partials.
__global__ __launch_bounds__(TPB) void scan_kernel(
    const int* __restrict__ duration,
    const int* __restrict__ tidx,   // (L, NNZ, 3) int32 (b, src, tgt)
    const float* __restrict__ tlv,  // (L, NNZ)
    const float* __restrict__ em,   // (B*T, N)
    float* __restrict__ part,       // [2][B][NPB][N] exp-sum partials
    float* __restrict__ Spart,      // [T][B][16] per-slice normalizer partials
    unsigned int* __restrict__ cnt, // [B*16] barrier counters (padded)
    float* __restrict__ out) {
  const int g = blockIdx.x;
  const int b = g / NPB, sl = g % NPB;
  const int tid = threadIdx.x;
  __shared__ float red[TPB / 64];
  __shared__ float lsb[Nc];

  const int node = sl * NODES_PER + tid;
  const size_t ebase = (size_t)b * (Nc * DEGc) + (size_t)node * DEGc;
  unsigned int* mycnt = cnt + b * 16;

  // zero the LDS scatter buffer
#pragma unroll
  for (int i = 0; i < Nc / TPB; ++i) lsb[i * TPB + tid] = 0.f;

  // ---- prologue: la0, 2-deep edge prefetch (rows 0,1), em(1) prefetch ----
  float la = em[((size_t)b * Tc) * Nc + node] - LOG_N;
  int4 c0, c1, c2; float4 cl;
  {
    const int4* ip = (const int4*)tidx + ((ebase * 3) >> 2);
    c0 = ip[0]; c1 = ip[1]; c2 = ip[2];
    cl = ((const float4*)tlv)[ebase >> 2];
  }
  int4 n0, n1, n2; float4 nl;
  {
    const size_t e = ebase + (size_t)NNZc;
    const int4* ip = (const int4*)tidx + ((e * 3) >> 2);
    n0 = ip[0]; n1 = ip[1]; n2 = ip[2];
    nl = ((const float4*)tlv)[e >> 2];
  }
  float em_nxt = em[((size_t)b * Tc + 1) * Nc + node];

  {
    float tot = blockSumT<TPB>(__expf(la), red);   // also fences lsb zeroing
    if (tid == 0) cohStoreF(&Spart[(0 * Bc + b) * 16 + sl], tot);
  }

  for (int t = 1; t <= Lc; ++t) {
    // ---- A: LDS scatter (consumes prefetched regs; ds_add_f32) ----
    atomicAdd(&lsb[c0.z], __expf(la + cl.x));
    atomicAdd(&lsb[c1.y], __expf(la + cl.y));
    atomicAdd(&lsb[c2.x], __expf(la + cl.z));
    atomicAdd(&lsb[c2.w], __expf(la + cl.w));
    __syncthreads();

    // write out my dense stripes (coalesced, device-scope) and re-zero LDS
    float* pp = part + (((size_t)(t & 1) * Bc + b) * NPB + sl) * Nc;
#pragma unroll
    for (int i = 0; i < Nc / TPB; ++i) {
      const int j = i * TPB + tid;
      float pv = lsb[j];
      lsb[j] = 0.f;                 // safe: each thread re-zeroes what it read
      cohStoreF(&pp[j], pv);
    }
    __syncthreads();                // drain global stores before arrival

    // ---- per-b grid barrier (monotone counter, NPB arrivals/step) ----
    if (tid == 0) {
      __hip_atomic_fetch_add(mycnt, 1u, __ATOMIC_RELAXED, __HIP_MEMORY_SCOPE_AGENT);
      const unsigned target = (unsigned)NPB * (unsigned)t;
      while (__hip_atomic_load(mycnt, __ATOMIC_RELAXED, __HIP_MEMORY_SCOPE_AGENT) < target)
        __builtin_amdgcn_s_sleep(1);
    }
    __syncthreads();                // release

    // ---- B: gather NPB partials + S[t-1] line (MALL, coalesced) ----
    const float* pbase = part + ((size_t)(t & 1) * Bc + b) * NPB * Nc;
    float pk[NPB];
#pragma unroll
    for (int k = 0; k < NPB; ++k) pk[k] = cohLoadF(&pbase[(size_t)k * Nc + node]);
    float Sprev = 0.f;
#pragma unroll
    for (int k = 0; k < NPB; ++k) Sprev += cohLoadF(&Spart[((size_t)(t - 1) * Bc + b) * 16 + k]);

    // issue next prefetches AFTER the gather loads (vmcnt is in-issue-order)
    int4 m0 = n0, m1 = n1, m2 = n2; float4 ml = nl;
    if (t <= Lc - 2) {
      const size_t e = (size_t)(t + 1) * NNZc + ebase;
      const int4* ip = (const int4*)tidx + ((e * 3) >> 2);
      m0 = ip[0]; m1 = ip[1]; m2 = ip[2];
      ml = ((const float4*)tlv)[e >> 2];
    }
    float em_fut = em_nxt;
    if (t < Lc) em_fut = em[((size_t)b * Tc + t + 1) * Nc + node];

    float sv = 0.f;
#pragma unroll
    for (int k = 0; k < NPB; ++k) sv += pk[k];
    const float v = __logf(sv) + em_nxt;          // em(t); sv>0 via self-loops
    float tot = blockSumT<TPB>(__expf(v), red);
    if (tid == 0) cohStoreF(&Spart[((size_t)t * Bc + b) * 16 + sl], tot);
    la = v - __logf(Sprev);

    c0 = n0; c1 = n1; c2 = n2; cl = nl;
    n0 = m0; n1 = m1; n2 = m2; nl = ml;
    em_nxt = em_fut;
  }

  // ---- final barrier so Spart[Lc] is globally visible ----
  __syncthreads();
  if (tid == 0) {
    __hip_atomic_fetch_add(mycnt, 1u, __ATOMIC_RELAXED, __HIP_MEMORY_SCOPE_AGENT);
    const unsigned target = (unsigned)NPB * (unsigned)Tc;
    while (__hip_atomic_load(mycnt, __ATOMIC_RELAXED, __HIP_MEMORY_SCOPE_AGENT) < target)
      __builtin_amdgcn_s_sleep(1);
  }
  __syncthreads();

  // out[b] = log S[t*] + sum_{tau<=t*-2} log S[tau]   (t* = duration[b]-1)
  if (sl == 0) {
    const int tstar = duration[b] - 1;
    float v = 0.0f;
    if (tid < Tc) {
      const int tau = tid;
      if (tau == tstar || tau <= tstar - 2) {
        float Sv = 0.f;
#pragma unroll
        for (int k = 0; k < NPB; ++k) Sv += cohLoadF(&Spart[((size_t)tau * Bc + b) * 16 + k]);
        v = __logf(Sv);
      }
    }
    float tot = blockSumT<TPB>(v, red);
    if (tid == 0) out[b] = tot;
  }
}

extern "C" void kernel_launch(void* const* d_in, const int* in_sizes, int n_in,
                              void* d_out, int out_size, void* d_ws, size_t ws_size,
                              hipStream_t stream) {
  const float* obs = (const float*)d_in[0];
  const float* W = (const float*)d_in[1];
  const int* duration = (const int*)d_in[2];
  const int* tidx = (const int*)d_in[3];
  const float* tlv = (const float*)d_in[4];
  float* out = (float*)d_out;

  float* em = (float*)d_ws;                                  // B*T*N floats (16 MB)
  float* part = em + (size_t)Bc * Tc * Nc;                   // 2*B*NPB*N floats (1 MB)
  float* Spart = part + (size_t)2 * Bc * NPB * Nc;           // T*B*16 floats (64 KB)
  unsigned int* cnt = (unsigned int*)(Spart + (size_t)Tc * Bc * 16);  // 64 uints

  hipMemsetAsync(cnt, 0, 64 * sizeof(unsigned int), stream);

  em_kernel<<<dim3(Bc * Tc), dim3(TPB_EM), 0, stream>>>(obs, W, em);
  scan_kernel<<<dim3(Bc * NPB), dim3(TPB), 0, stream>>>(duration, tidx, tlv, em,
                                                        part, Spart, cnt, out);
}